// Round 10
// baseline (302.987 us; speedup 1.0000x reference)
//
#include <hip/hip_runtime.h>
#include <hip/hip_bf16.h>

#define NB 4096
#define MB 1024
#define SZ ((size_t)MB * NB)
#define NN ((size_t)NB * NB)

typedef __bf16 bf16_t;
typedef __attribute__((ext_vector_type(8))) __bf16 bf16x8;
typedef __attribute__((ext_vector_type(4))) float f32x4;
typedef __attribute__((ext_vector_type(4))) unsigned int u32x4;

#define AS1 __attribute__((address_space(1)))
#define AS3 __attribute__((address_space(3)))
#define GLOAD16(gp, lp)                                                        \
  __builtin_amdgcn_global_load_lds((const AS1 unsigned int*)(gp),              \
                                   (AS3 unsigned int*)(lp), 16, 0, 0)
#define SBAR() __builtin_amdgcn_s_barrier()
#define SCHEDB() __builtin_amdgcn_sched_barrier(0)
#define MFMA16(a, b, c) __builtin_amdgcn_mfma_f32_16x16x32_bf16((a), (b), (c), 0, 0, 0)
#define VMCNT4() asm volatile("s_waitcnt vmcnt(4)" ::: "memory")
#define VMCNT0() asm volatile("s_waitcnt vmcnt(0)" ::: "memory")
#define LGKM0() asm volatile("s_waitcnt lgkmcnt(0)" ::: "memory")
// volatile asm ds_read: mutually ordered with barrier asm, cannot be sunk
// into the MFMA cluster by the scheduler (r9 lesson: intrinsic loads were).
#define DSREAD128(dst, addr)                                                   \
  asm volatile("ds_read_b128 %0, %1" : "=v"(dst) : "v"(addr))

// Half-K-tile LDS layout (verified 0-conflict r7): [rows][32 k] bf16, cells
// of 8 bf16; cell (r,c) at slot c ^ ((r>>1)&3). gload_lds writes linearly
// (lane l -> row base+(l>>2), slot l&3); global source chunk (l&3)^((l>>3)&3).
// Read of k-chunk kq at row 16a+lr: slot kq^((lr>>1)&3).
// Sync (verified passing r9): ring-4 slots, prefetch distance 3, one
// {vmcnt(4); s_barrier} per half (tail 0). Slot h+1 is globally confirmed at
// the end of half h-1, so reading slot h+1's frags during half h is safe.

__device__ __forceinline__ bf16x8 asbf(u32x4 x) {
  bf16x8 y;
  __builtin_memcpy(&y, &x, 16);
  return y;
}

__device__ __forceinline__ bf16x8 asbf_neg(u32x4 x) {
  x ^= 0x80008000u;
  bf16x8 y;
  __builtin_memcpy(&y, &x, 16);
  return y;
}

__device__ __forceinline__ bf16x8 cvt8(float4 a, float4 b) {
  bf16x8 v;
  v[0] = (bf16_t)a.x; v[1] = (bf16_t)a.y; v[2] = (bf16_t)a.z; v[3] = (bf16_t)a.w;
  v[4] = (bf16_t)b.x; v[5] = (bf16_t)b.y; v[6] = (bf16_t)b.z; v[7] = (bf16_t)b.w;
  return v;
}

// ---------------- prep: f32 -> bf16 ----------------
#define ITEM_S (SZ / 8)
#define ITEM_N (NN / 8)

__global__ __launch_bounds__(256) void prep6_kernel(
    const float* __restrict__ u, const float* __restrict__ w,
    const float* __restrict__ G, const float* __restrict__ Bm,
    const float* __restrict__ Wp, const float* __restrict__ Wq,
    bf16_t* __restrict__ ws) {
  size_t stride = (size_t)gridDim.x * blockDim.x;
  const size_t tot = 2 * ITEM_S + 4 * ITEM_N;
  for (size_t i = (size_t)blockIdx.x * blockDim.x + threadIdx.x; i < tot;
       i += stride) {
    const float* src;
    bf16_t* dst;
    size_t off;
    if (i < ITEM_S) { src = u; dst = ws; off = i; }
    else if (i < 2 * ITEM_S) { src = w; dst = ws + SZ; off = i - ITEM_S; }
    else if (i < 2 * ITEM_S + ITEM_N) { src = G; dst = ws + 2 * SZ; off = i - 2 * ITEM_S; }
    else if (i < 2 * ITEM_S + 2 * ITEM_N) { src = Bm; dst = ws + 2 * SZ + NN; off = i - 2 * ITEM_S - ITEM_N; }
    else if (i < 2 * ITEM_S + 3 * ITEM_N) { src = Wp; dst = ws + 2 * SZ + 2 * NN; off = i - 2 * ITEM_S - 2 * ITEM_N; }
    else { src = Wq; dst = ws + 2 * SZ + 3 * NN; off = i - 2 * ITEM_S - 3 * ITEM_N; }
    const float4* s = reinterpret_cast<const float4*>(src) + off * 2;
    reinterpret_cast<bf16x8*>(dst)[off] = cvt8(s[0], s[1]);
  }
}

__global__ __launch_bounds__(256) void prep4_kernel(
    const float* __restrict__ u, const float* __restrict__ w,
    const float* __restrict__ G, const float* __restrict__ Bm,
    bf16_t* __restrict__ ws) {
  size_t stride = (size_t)gridDim.x * blockDim.x;
  const size_t tot = 2 * ITEM_S + 2 * ITEM_N;
  for (size_t i = (size_t)blockIdx.x * blockDim.x + threadIdx.x; i < tot;
       i += stride) {
    const float* src;
    bf16_t* dst;
    size_t off;
    if (i < ITEM_S) { src = u; dst = ws; off = i; }
    else if (i < 2 * ITEM_S) { src = w; dst = ws + SZ; off = i - ITEM_S; }
    else if (i < 2 * ITEM_S + ITEM_N) { src = G; dst = ws + 2 * SZ; off = i - 2 * ITEM_S; }
    else { src = Bm; dst = ws + 2 * SZ + NN; off = i - 2 * ITEM_S - ITEM_N; }
    const float4* s = reinterpret_cast<const float4*>(src) + off * 2;
    reinterpret_cast<bf16x8*>(dst)[off] = cvt8(s[0], s[1]);
  }
}

struct F1Frag { u32x4 au[4], aw[4], bG[2], bB[2]; };
struct G2Frag { u32x4 av[4], bw[4]; };

#define SYNC_HALF(hh)                                                          \
  do {                                                                         \
    if ((hh) <= 124) { VMCNT4(); SBAR(); }                                     \
    else if ((hh) == 125) { VMCNT0(); SBAR(); }                                \
    SCHEDB();                                                                  \
  } while (0)

// ---------------- fused stage 1: asm-pinned rotation pipeline -------------
// S = u@G^T - w@B^T, T = w@G^T + u@B^T; p_mid/q_mid epilogue (bf16).
// Tile 128x128, 8 waves (2m x 4n, wave 64x32), ring-4 (128 KB).
// Per half/wave: lgkmcnt(0) -> 12 asm ds_read (NEXT half) + 4 gload_lds
// issue + 32 MFMA (current regs) -> vmcnt(4)+barrier.
__global__ __launch_bounds__(512, 2) void fused1_v8(
    const float* __restrict__ u, const float* __restrict__ w,
    const bf16_t* __restrict__ ubf, const bf16_t* __restrict__ wbf,
    const bf16_t* __restrict__ Gbf, const bf16_t* __restrict__ Bbf,
    const float* __restrict__ bias_p, const float* __restrict__ bias_q,
    bf16_t* __restrict__ pq) {
  __shared__ bf16_t lds[4][4][128 * 32];  // [slot][op][row*32] = 128 KB
  const int tid = threadIdx.x, lane = tid & 63, wv = tid >> 6;
  const int bid = blockIdx.x;
  const int t = (bid & 7) * 32 + (bid >> 3);  // XCD swizzle, 256 blocks
  const int row0 = (t & 7) * 128, col0 = (t >> 3) * 128;
  const int wm = (wv >> 2) * 64, wn = (wv & 3) * 32;
  const int lr = lane & 15, kq = lane >> 4;
  const int kswz = (kq ^ ((lr >> 1) & 3)) << 3;

  const int srow = wv * 16 + (lane >> 2);
  const int sc = (lane & 3) ^ ((lane >> 3) & 3);
  const bf16_t* gsrc[4];
  gsrc[0] = ubf + (size_t)(row0 + srow) * NB + sc * 8;
  gsrc[1] = wbf + (size_t)(row0 + srow) * NB + sc * 8;
  gsrc[2] = Gbf + (size_t)(col0 + srow) * NB + sc * 8;
  gsrc[3] = Bbf + (size_t)(col0 + srow) * NB + sc * 8;

#define F1_ISSUE(hh)                                                           \
  do {                                                                         \
    const int _sl = (hh) & 3;                                                  \
    const int _ko = (hh) * 32;                                                 \
    GLOAD16(gsrc[0] + _ko, &lds[_sl][0][wv * 512]);                            \
    GLOAD16(gsrc[1] + _ko, &lds[_sl][1][wv * 512]);                            \
    GLOAD16(gsrc[2] + _ko, &lds[_sl][2][wv * 512]);                            \
    GLOAD16(gsrc[3] + _ko, &lds[_sl][3][wv * 512]);                            \
  } while (0)

  // byte offsets for asm ds_read
  const unsigned ldsb = (unsigned)(uintptr_t)(AS3 bf16_t*)&lds[0][0][0];
  unsigned aob[4], bob[2];
#pragma unroll
  for (int m = 0; m < 4; ++m) aob[m] = ((wm + m * 16 + lr) * 32 + kswz) * 2;
#pragma unroll
  for (int n = 0; n < 2; ++n) bob[n] = ((wn + n * 16 + lr) * 32 + kswz) * 2;

#define F1_READ(F, sl)                                                         \
  do {                                                                         \
    const unsigned _sb = ldsb + (unsigned)(sl) * 32768u;                       \
    DSREAD128((F).bG[0], _sb + 2u * 8192u + bob[0]);                           \
    DSREAD128((F).bG[1], _sb + 2u * 8192u + bob[1]);                           \
    DSREAD128((F).bB[0], _sb + 3u * 8192u + bob[0]);                           \
    DSREAD128((F).bB[1], _sb + 3u * 8192u + bob[1]);                           \
    DSREAD128((F).au[0], _sb + aob[0]);                                        \
    DSREAD128((F).au[1], _sb + aob[1]);                                        \
    DSREAD128((F).au[2], _sb + aob[2]);                                        \
    DSREAD128((F).au[3], _sb + aob[3]);                                        \
    DSREAD128((F).aw[0], _sb + 8192u + aob[0]);                                \
    DSREAD128((F).aw[1], _sb + 8192u + aob[1]);                                \
    DSREAD128((F).aw[2], _sb + 8192u + aob[2]);                                \
    DSREAD128((F).aw[3], _sb + 8192u + aob[3]);                                \
  } while (0)

#define F1_MFMA(F)                                                             \
  do {                                                                         \
    bf16x8 _bG0 = asbf((F).bG[0]), _bG1 = asbf((F).bG[1]);                     \
    bf16x8 _bB0 = asbf((F).bB[0]), _bB1 = asbf((F).bB[1]);                     \
    bf16x8 _nB0 = asbf_neg((F).bB[0]), _nB1 = asbf_neg((F).bB[1]);             \
    _Pragma("unroll") for (int _m = 0; _m < 4; ++_m) {                         \
      bf16x8 _au = asbf((F).au[_m]), _aw = asbf((F).aw[_m]);                   \
      aS[_m][0] = MFMA16(_au, _bG0, aS[_m][0]);                                \
      aS[_m][0] = MFMA16(_aw, _nB0, aS[_m][0]);                                \
      aT[_m][0] = MFMA16(_aw, _bG0, aT[_m][0]);                                \
      aT[_m][0] = MFMA16(_au, _bB0, aT[_m][0]);                                \
      aS[_m][1] = MFMA16(_au, _bG1, aS[_m][1]);                                \
      aS[_m][1] = MFMA16(_aw, _nB1, aS[_m][1]);                                \
      aT[_m][1] = MFMA16(_aw, _bG1, aT[_m][1]);                                \
      aT[_m][1] = MFMA16(_au, _bB1, aT[_m][1]);                                \
    }                                                                          \
  } while (0)

  f32x4 aS[4][2] = {}, aT[4][2] = {};
  F1Frag fA, fB;

  // prologue: issue halves 0,1,2; confirm 0,1; asm-read frags of half 0
  F1_ISSUE(0); F1_ISSUE(1); F1_ISSUE(2);
  VMCNT4();
  SBAR();
  SCHEDB();
  F1_READ(fA, 0);

  for (int h = 0; h < 128; h += 2) {
    // even half h: consume fA, asm-read h+1 into fB
    LGKM0();
    SCHEDB();
    if (h + 1 < 128) F1_READ(fB, (h + 1) & 3);
    if (h + 3 < 128) F1_ISSUE(h + 3);
    F1_MFMA(fA);
    SYNC_HALF(h);
    // odd half h+1: consume fB, asm-read h+2 into fA
    LGKM0();
    SCHEDB();
    if (h + 2 < 128) F1_READ(fA, (h + 2) & 3);
    if (h + 4 < 128) F1_ISSUE(h + 4);
    F1_MFMA(fB);
    SYNC_HALF(h + 1);
  }

  // epilogue: combine with u,w (f32) + biases -> p_mid/q_mid bf16
  const int fr = lane & 15, fq = kq;
#pragma unroll
  for (int m = 0; m < 4; ++m)
#pragma unroll
    for (int n = 0; n < 2; ++n)
#pragma unroll
      for (int j = 0; j < 4; ++j) {
        int r = row0 + wm + m * 16 + fq * 4 + j;
        int c = col0 + wn + n * 16 + fr;
        size_t idx = (size_t)r * NB + c;
        float U = u[idx], W = w[idx];
        float S = aS[m][n][j], T = aT[m][n][j];
        pq[idx] = (bf16_t)(U * S + W * T + bias_p[c]);
        pq[SZ + idx] = (bf16_t)(W * S - U * T + bias_q[c]);
      }
}

// ---------------- stage 2: asm-pinned rotation, 2 blocks/CU ----------------
// out_z = pq_z @ W_z^T + b_z (f32). Tile 128x128, 4 waves (2x2, wave 64x64),
// ring-4 (64 KB -> 2 blocks/CU). Per half/wave: 8 asm ds_read (next) +
// 4 gload_lds + 16 MFMA. Grid 512, XCD-swizzled.
__global__ __launch_bounds__(256, 2) void gemm2_v9(
    const bf16_t* __restrict__ pq, const bf16_t* __restrict__ Wpb,
    const bf16_t* __restrict__ Wqb, const float* __restrict__ bp,
    const float* __restrict__ bq, float* __restrict__ out) {
  __shared__ bf16_t lds[4][2][128 * 32];  // [slot][A/W] = 64 KB
  const int tid = threadIdx.x, lane = tid & 63, wv = tid >> 6;
  const int bid = blockIdx.x;
  const int t = (bid & 7) * 64 + (bid >> 3);  // XCD swizzle, 512 blocks
  const int z = t >> 8;
  const int s = t & 255;
  const int row0 = (s & 7) * 128, col0 = (s >> 3) * 128;

  const bf16_t* A = pq + (size_t)z * SZ;
  const bf16_t* Wm = z ? Wqb : Wpb;
  const float* bias = z ? bq : bp;
  float* C = out + (size_t)z * SZ;

  const int wm = (wv >> 1) * 64, wn = (wv & 1) * 64;
  const int lr = lane & 15, kq = lane >> 4;
  const int kswz = (kq ^ ((lr >> 1) & 3)) << 3;

  const int srow = tid >> 2;  // 0..63
  const int sc = (tid & 3) ^ ((tid >> 3) & 3);
  const bf16_t* gA0 = A + (size_t)(row0 + srow) * NB + sc * 8;
  const bf16_t* gA1 = gA0 + (size_t)64 * NB;
  const bf16_t* gW0 = Wm + (size_t)(col0 + srow) * NB + sc * 8;
  const bf16_t* gW1 = gW0 + (size_t)64 * NB;

#define G2_ISSUE(hh)                                                           \
  do {                                                                         \
    const int _sl = (hh) & 3;                                                  \
    const int _ko = (hh) * 32;                                                 \
    GLOAD16(gA0 + _ko, &lds[_sl][0][wv * 512]);                                \
    GLOAD16(gA1 + _ko, &lds[_sl][0][2048 + wv * 512]);                         \
    GLOAD16(gW0 + _ko, &lds[_sl][1][wv * 512]);                                \
    GLOAD16(gW1 + _ko, &lds[_sl][1][2048 + wv * 512]);                         \
  } while (0)

  const unsigned ldsb = (unsigned)(uintptr_t)(AS3 bf16_t*)&lds[0][0][0];
  unsigned aob[4], wob[4];
#pragma unroll
  for (int m = 0; m < 4; ++m) aob[m] = ((wm + m * 16 + lr) * 32 + kswz) * 2;
#pragma unroll
  for (int n = 0; n < 4; ++n) wob[n] = ((wn + n * 16 + lr) * 32 + kswz) * 2;

#define G2_READ(F, sl)                                                         \
  do {                                                                         \
    const unsigned _sb = ldsb + (unsigned)(sl) * 16384u;                       \
    DSREAD128((F).av[0], _sb + aob[0]);                                        \
    DSREAD128((F).av[1], _sb + aob[1]);                                        \
    DSREAD128((F).av[2], _sb + aob[2]);                                        \
    DSREAD128((F).av[3], _sb + aob[3]);                                        \
    DSREAD128((F).bw[0], _sb + 8192u + wob[0]);                                \
    DSREAD128((F).bw[1], _sb + 8192u + wob[1]);                                \
    DSREAD128((F).bw[2], _sb + 8192u + wob[2]);                                \
    DSREAD128((F).bw[3], _sb + 8192u + wob[3]);                                \
  } while (0)

#define G2_MFMA(F)                                                             \
  do {                                                                         \
    bf16x8 _bw0 = asbf((F).bw[0]), _bw1 = asbf((F).bw[1]);                     \
    bf16x8 _bw2 = asbf((F).bw[2]), _bw3 = asbf((F).bw[3]);                     \
    _Pragma("unroll") for (int _m = 0; _m < 4; ++_m) {                         \
      bf16x8 _av = asbf((F).av[_m]);                                           \
      acc[_m][0] = MFMA16(_av, _bw0, acc[_m][0]);                              \
      acc[_m][1] = MFMA16(_av, _bw1, acc[_m][1]);                              \
      acc[_m][2] = MFMA16(_av, _bw2, acc[_m][2]);                              \
      acc[_m][3] = MFMA16(_av, _bw3, acc[_m][3]);                              \
    }                                                                          \
  } while (0)

  f32x4 acc[4][4] = {};
  G2Frag fA, fB;

  G2_ISSUE(0); G2_ISSUE(1); G2_ISSUE(2);
  VMCNT4();
  SBAR();
  SCHEDB();
  G2_READ(fA, 0);

  for (int h = 0; h < 128; h += 2) {
    LGKM0();
    SCHEDB();
    if (h + 1 < 128) G2_READ(fB, (h + 1) & 3);
    if (h + 3 < 128) G2_ISSUE(h + 3);
    G2_MFMA(fA);
    SYNC_HALF(h);
    LGKM0();
    SCHEDB();
    if (h + 2 < 128) G2_READ(fA, (h + 2) & 3);
    if (h + 4 < 128) G2_ISSUE(h + 4);
    G2_MFMA(fB);
    SYNC_HALF(h + 1);
  }

  const int fr = lane & 15, fq = kq;
#pragma unroll
  for (int m = 0; m < 4; ++m)
#pragma unroll
    for (int n = 0; n < 4; ++n)
#pragma unroll
      for (int j = 0; j < 4; ++j) {
        int r = row0 + wm + m * 16 + fq * 4 + j;
        int c = col0 + wn + n * 16 + fr;
        C[(size_t)r * NB + c] = acc[m][n][j] + bias[c];
      }
}

// ---------------- fallbacks (compile-only safety net) ----------------
__device__ __forceinline__ int swz_off32(int r, int kk) {
  return r * 32 + ((kk ^ ((r >> 1) & 3)) << 3);
}

__device__ __forceinline__ bf16x8 neg8(bf16x8 x) {
  u32x4 t;
  __builtin_memcpy(&t, &x, 16);
  t ^= 0x80008000u;
  bf16x8 y;
  __builtin_memcpy(&y, &t, 16);
  return y;
}

__device__ __forceinline__ void fb_stage_f32(const float* __restrict__ src,
                                             int row0, int k0, bf16_t* lds, int t) {
  int r = t >> 2, kk = t & 3;
  const float* p = src + (size_t)(row0 + r) * NB + k0 + (kk << 3);
  float4 v0 = *reinterpret_cast<const float4*>(p);
  float4 v1 = *reinterpret_cast<const float4*>(p + 4);
  *reinterpret_cast<bf16x8*>(lds + swz_off32(r, kk)) = cvt8(v0, v1);
}

__global__ __launch_bounds__(256, 2) void fb_gemm2(
    const bf16_t* __restrict__ pq, const float* __restrict__ Wp,
    const float* __restrict__ Wq, const float* __restrict__ bp,
    const float* __restrict__ bq, float* __restrict__ out) {
  __shared__ bf16_t lA[128 * 32], lW[128 * 32];
  const int z = blockIdx.z;
  const bf16_t* A = pq + (size_t)z * SZ;
  const float* Wm = z ? Wq : Wp;
  const float* bias = z ? bq : bp;
  float* C = out + (size_t)z * SZ;
  const int tid = threadIdx.x;
  const int lane = tid & 63, wv = tid >> 6;
  const int wm = (wv >> 1) * 64, wn = (wv & 1) * 64;
  const int row0 = blockIdx.y * 128, col0 = blockIdx.x * 128;
  const int lr = lane & 15, kq = lane >> 4;
  const int fslot = (kq ^ ((lr >> 1) & 3)) << 3;
  f32x4 acc[4][4] = {};
  for (int kt = 0; kt < NB; kt += 32) {
#pragma unroll
    for (int p = 0; p < 2; ++p) {
      int cb = p * 256 + wv * 64;
      int ci = cb + lane;
      int r = ci >> 2, kl = ci & 3;
      int ks = kl ^ ((r >> 1) & 3);
      const bf16_t* g = A + (size_t)(row0 + r) * NB + kt + (ks << 3);
      GLOAD16(g, lA + cb * 8);
    }
#pragma unroll
    for (int p = 0; p < 2; ++p)
      fb_stage_f32(Wm, col0, kt, lW, p * 256 + tid);
    __syncthreads();
    bf16x8 af[4], bg[4];
#pragma unroll
    for (int m = 0; m < 4; ++m)
      af[m] = *reinterpret_cast<const bf16x8*>(lA + (wm + m * 16 + lr) * 32 + fslot);
#pragma unroll
    for (int n = 0; n < 4; ++n)
      bg[n] = *reinterpret_cast<const bf16x8*>(lW + (wn + n * 16 + lr) * 32 + fslot);
#pragma unroll
    for (int m = 0; m < 4; ++m)
#pragma unroll
      for (int n = 0; n < 4; ++n)
        acc[m][n] = MFMA16(af[m], bg[n], acc[m][n]);
    __syncthreads();
  }
  const int fr = lane & 15, fq = lane >> 4;
#pragma unroll
  for (int m = 0; m < 4; ++m)
#pragma unroll
    for (int n = 0; n < 4; ++n)
#pragma unroll
      for (int j = 0; j < 4; ++j) {
        int r = row0 + wm + m * 16 + fq * 4 + j;
        int c = col0 + wn + n * 16 + fr;
        C[(size_t)r * NB + c] = acc[m][n][j] + bias[c];
      }
}

__global__ __launch_bounds__(512, 2) void fb_fused1(
    const float* __restrict__ u, const float* __restrict__ w,
    const float* __restrict__ G, const float* __restrict__ Bm,
    const float* __restrict__ bias_p, const float* __restrict__ bias_q,
    bf16_t* __restrict__ pq) {
  __shared__ bf16_t lU[128 * 32], lW[128 * 32], lG[128 * 32], lB[128 * 32];
  const int tid = threadIdx.x;
  const int lane = tid & 63, wv = tid >> 6;
  const int wm = (wv >> 2) * 64, wn = (wv & 3) * 32;
  const int row0 = blockIdx.y * 128, col0 = blockIdx.x * 128;
  const int lr = lane & 15, kq = lane >> 4;
  const int fslot = (kq ^ ((lr >> 1) & 3)) << 3;
  f32x4 aS[4][2] = {}, aT[4][2] = {};
  for (int kt = 0; kt < NB; kt += 32) {
    fb_stage_f32(u, row0, kt, lU, tid);
    fb_stage_f32(w, row0, kt, lW, tid);
    fb_stage_f32(G, col0, kt, lG, tid);
    fb_stage_f32(Bm, col0, kt, lB, tid);
    __syncthreads();
    bf16x8 au[4], aw[4], bG[2], bB[2], bBn[2];
#pragma unroll
    for (int m = 0; m < 4; ++m) {
      int off = (wm + m * 16 + lr) * 32 + fslot;
      au[m] = *reinterpret_cast<const bf16x8*>(lU + off);
      aw[m] = *reinterpret_cast<const bf16x8*>(lW + off);
    }
#pragma unroll
    for (int n = 0; n < 2; ++n) {
      int off = (wn + n * 16 + lr) * 32 + fslot;
      bG[n] = *reinterpret_cast<const bf16x8*>(lG + off);
      bB[n] = *reinterpret_cast<const bf16x8*>(lB + off);
      bBn[n] = neg8(bB[n]);
    }
#pragma unroll
    for (int m = 0; m < 4; ++m)
#pragma unroll
      for (int n = 0; n < 2; ++n) {
        aS[m][n] = MFMA16(au[m], bG[n], aS[m][n]);
        aS[m][n] = MFMA16(aw[m], bBn[n], aS[m][n]);
        aT[m][n] = MFMA16(aw[m], bG[n], aT[m][n]);
        aT[m][n] = MFMA16(au[m], bB[n], aT[m][n]);
      }
    __syncthreads();
  }
  const int fr = lane & 15, fq = lane >> 4;
#pragma unroll
  for (int m = 0; m < 4; ++m)
#pragma unroll
    for (int n = 0; n < 2; ++n)
#pragma unroll
      for (int j = 0; j < 4; ++j) {
        int r = row0 + wm + m * 16 + fq * 4 + j;
        int c = col0 + wn + n * 16 + fr;
        size_t idx = (size_t)r * NB + c;
        float U = u[idx], W = w[idx];
        float S = aS[m][n][j], T = aT[m][n][j];
        pq[idx] = (bf16_t)(U * S + W * T + bias_p[c]);
        pq[SZ + idx] = (bf16_t)(W * S - U * T + bias_q[c]);
      }
}

extern "C" void kernel_launch(void* const* d_in, const int* in_sizes, int n_in,
                              void* d_out, int out_size, void* d_ws, size_t ws_size,
                              hipStream_t stream) {
  const float* u = (const float*)d_in[0];
  const float* w = (const float*)d_in[1];
  const float* G = (const float*)d_in[2];
  const float* Bm = (const float*)d_in[3];
  const float* bias_p = (const float*)d_in[4];
  const float* bias_q = (const float*)d_in[5];
  const float* Wp = (const float*)d_in[6];
  const float* bp = (const float*)d_in[7];
  const float* Wq = (const float*)d_in[8];
  const float* bq = (const float*)d_in[9];
  (void)in_sizes; (void)n_in; (void)out_size;

  const size_t need_full = (6 * SZ + 4 * NN) * sizeof(bf16_t);  // 176 MB
  const size_t need_mid = (6 * SZ + 2 * NN) * sizeof(bf16_t);   // 112 MB

  if (ws_size >= need_full) {
    bf16_t* ws = (bf16_t*)d_ws;
    bf16_t* ubf = ws;
    bf16_t* wbf = ws + SZ;
    bf16_t* Gbf = ws + 2 * SZ;
    bf16_t* Bbf = Gbf + NN;
    bf16_t* Wpb = Bbf + NN;
    bf16_t* Wqb = Wpb + NN;
    bf16_t* pqw = Wqb + NN;
    prep6_kernel<<<2048, 256, 0, stream>>>(u, w, G, Bm, Wp, Wq, ws);
    fused1_v8<<<256, 512, 0, stream>>>(u, w, ubf, wbf, Gbf, Bbf,
                                       bias_p, bias_q, pqw);
    gemm2_v9<<<512, 256, 0, stream>>>(pqw, Wpb, Wqb, bp, bq, (float*)d_out);
  } else if (ws_size >= need_mid) {
    bf16_t* ws = (bf16_t*)d_ws;
    bf16_t* ubf = ws;
    bf16_t* wbf = ws + SZ;
    bf16_t* Gbf = ws + 2 * SZ;
    bf16_t* Bbf = Gbf + NN;
    bf16_t* pqw = Bbf + NN;
    prep4_kernel<<<2048, 256, 0, stream>>>(u, w, G, Bm, ws);
    fused1_v8<<<256, 512, 0, stream>>>(u, w, ubf, wbf, Gbf, Bbf,
                                       bias_p, bias_q, pqw);
    fb_gemm2<<<dim3(NB / 128, MB / 128, 2), 256, 0, stream>>>(
        pqw, Wp, Wq, bp, bq, (float*)d_out);
  } else {
    bf16_t* pqw = (bf16_t*)d_ws;
    fb_fused1<<<dim3(NB / 128, MB / 128), 512, 0, stream>>>(
        u, w, G, Bm, bias_p, bias_q, pqw);
    fb_gemm2<<<dim3(NB / 128, MB / 128, 2), 256, 0, stream>>>(
        pqw, Wp, Wq, bp, bq, (float*)d_out);
  }
}

// Round 11
// 302.514 us; speedup vs baseline: 1.0016x; 1.0016x over previous
//
#include <hip/hip_runtime.h>
#include <hip/hip_bf16.h>

#define NB 4096
#define MB 1024
#define SZ ((size_t)MB * NB)
#define NN ((size_t)NB * NB)

typedef __bf16 bf16_t;
typedef __attribute__((ext_vector_type(8))) __bf16 bf16x8;
typedef __attribute__((ext_vector_type(4))) float f32x4;
typedef __attribute__((ext_vector_type(4))) unsigned int u32x4;

#define AS1 __attribute__((address_space(1)))
#define AS3 __attribute__((address_space(3)))
#define GLOAD16(gp, lp)                                                        \
  __builtin_amdgcn_global_load_lds((const AS1 unsigned int*)(gp),              \
                                   (AS3 unsigned int*)(lp), 16, 0, 0)
#define SBAR() __builtin_amdgcn_s_barrier()
#define SCHEDB() __builtin_amdgcn_sched_barrier(0)
#define MFMA16(a, b, c) __builtin_amdgcn_mfma_f32_16x16x32_bf16((a), (b), (c), 0, 0, 0)
#define VMCNT4() asm volatile("s_waitcnt vmcnt(4)" ::: "memory")
#define VMCNT0() asm volatile("s_waitcnt vmcnt(0)" ::: "memory")

__device__ __forceinline__ bf16x8 neg8(bf16x8 x) {
  u32x4 t;
  __builtin_memcpy(&t, &x, 16);
  t ^= 0x80008000u;
  bf16x8 y;
  __builtin_memcpy(&y, &t, 16);
  return y;
}

__device__ __forceinline__ bf16x8 cvt8(float4 a, float4 b) {
  bf16x8 v;
  v[0] = (bf16_t)a.x; v[1] = (bf16_t)a.y; v[2] = (bf16_t)a.z; v[3] = (bf16_t)a.w;
  v[4] = (bf16_t)b.x; v[5] = (bf16_t)b.y; v[6] = (bf16_t)b.z; v[7] = (bf16_t)b.w;
  return v;
}

// ---------------- prep: f32 -> bf16 ----------------
#define ITEM_S (SZ / 8)
#define ITEM_N (NN / 8)

__global__ __launch_bounds__(256) void prep6_kernel(
    const float* __restrict__ u, const float* __restrict__ w,
    const float* __restrict__ G, const float* __restrict__ Bm,
    const float* __restrict__ Wp, const float* __restrict__ Wq,
    bf16_t* __restrict__ ws) {
  size_t stride = (size_t)gridDim.x * blockDim.x;
  const size_t tot = 2 * ITEM_S + 4 * ITEM_N;
  for (size_t i = (size_t)blockIdx.x * blockDim.x + threadIdx.x; i < tot;
       i += stride) {
    const float* src;
    bf16_t* dst;
    size_t off;
    if (i < ITEM_S) { src = u; dst = ws; off = i; }
    else if (i < 2 * ITEM_S) { src = w; dst = ws + SZ; off = i - ITEM_S; }
    else if (i < 2 * ITEM_S + ITEM_N) { src = G; dst = ws + 2 * SZ; off = i - 2 * ITEM_S; }
    else if (i < 2 * ITEM_S + 2 * ITEM_N) { src = Bm; dst = ws + 2 * SZ + NN; off = i - 2 * ITEM_S - ITEM_N; }
    else if (i < 2 * ITEM_S + 3 * ITEM_N) { src = Wp; dst = ws + 2 * SZ + 2 * NN; off = i - 2 * ITEM_S - 2 * ITEM_N; }
    else { src = Wq; dst = ws + 2 * SZ + 3 * NN; off = i - 2 * ITEM_S - 3 * ITEM_N; }
    const float4* s = reinterpret_cast<const float4*>(src) + off * 2;
    reinterpret_cast<bf16x8*>(dst)[off] = cvt8(s[0], s[1]);
  }
}

__global__ __launch_bounds__(256) void prep4_kernel(
    const float* __restrict__ u, const float* __restrict__ w,
    const float* __restrict__ G, const float* __restrict__ Bm,
    bf16_t* __restrict__ ws) {
  size_t stride = (size_t)gridDim.x * blockDim.x;
  const size_t tot = 2 * ITEM_S + 2 * ITEM_N;
  for (size_t i = (size_t)blockIdx.x * blockDim.x + threadIdx.x; i < tot;
       i += stride) {
    const float* src;
    bf16_t* dst;
    size_t off;
    if (i < ITEM_S) { src = u; dst = ws; off = i; }
    else if (i < 2 * ITEM_S) { src = w; dst = ws + SZ; off = i - ITEM_S; }
    else if (i < 2 * ITEM_S + ITEM_N) { src = G; dst = ws + 2 * SZ; off = i - 2 * ITEM_S; }
    else { src = Bm; dst = ws + 2 * SZ + NN; off = i - 2 * ITEM_S - ITEM_N; }
    const float4* s = reinterpret_cast<const float4*>(src) + off * 2;
    reinterpret_cast<bf16x8*>(dst)[off] = cvt8(s[0], s[1]);
  }
}

// ---------------- fused stage 1: 8-phase schedule (r4's v3, best=120us) ----
// S = u@G^T - w@B^T, T = w@G^T + u@B^T; p_mid = u*S + w*T + bias_p,
// q_mid = w*S - u*T + bias_q (bf16 out).
// Tile 128x128, BK=64, 512 thr / 8 waves (2m x 4n, wave 64x32), LDS 128KB.
// Per K-tile: 4 phases {ds_read frags | prefetch issue | barrier | 16 MFMA |
// barrier}; vmcnt(0) once per K-tile (prefetch issued phases 0-1).
// LDS cell layout: row r (0..127) x 8 chunks of 8 bf16; chunk c at slot
// c ^ (r&7); read kread[ks] = ((ks*4+kq) ^ (lr&7))*8.
__global__ __launch_bounds__(512, 2) void fused1_v3(
    const float* __restrict__ u, const float* __restrict__ w,
    const bf16_t* __restrict__ ubf, const bf16_t* __restrict__ wbf,
    const bf16_t* __restrict__ Gbf, const bf16_t* __restrict__ Bbf,
    const float* __restrict__ bias_p, const float* __restrict__ bias_q,
    bf16_t* __restrict__ pq) {
  __shared__ bf16_t lds[2][4][128 * 64];  // 128 KB
  const int tid = threadIdx.x, lane = tid & 63, wv = tid >> 6;
  const int bid = blockIdx.x;
  const int t = (bid & 7) * 32 + (bid >> 3);  // XCD swizzle, 256 blocks
  const int row0 = (t & 7) * 128, col0 = (t >> 3) * 128;
  const int wm = (wv >> 2) * 64, wn = (wv & 3) * 32;
  const int lr = lane & 15, kq = lane >> 4;

  // staging: thread stages 2 cells per op (rows rA and rA+64, same chunk)
  const int rA = tid >> 3;
  const int kkc = (tid & 7) ^ (rA & 7);
  const bf16_t* bases[4] = {ubf, wbf, Gbf, Bbf};
  const int r0s[4] = {row0, row0, col0, col0};
  const bf16_t* gsA[4];
  const bf16_t* gsB[4];
#pragma unroll
  for (int o = 0; o < 4; ++o) {
    gsA[o] = bases[o] + (size_t)(r0s[o] + rA) * NB + kkc * 8;
    gsB[o] = gsA[o] + (size_t)64 * NB;
  }

#define F1_ST(bufv, o, ktn)                                                    \
  do {                                                                         \
    GLOAD16(gsA[o] + (ktn), &lds[bufv][o][wv * 512]);                          \
    GLOAD16(gsB[o] + (ktn), &lds[bufv][o][4096 + wv * 512]);                   \
  } while (0)

  // frag read offsets (bf16 units)
  int kread[2], aoff[4], boff[2];
#pragma unroll
  for (int ks = 0; ks < 2; ++ks) kread[ks] = ((ks * 4 + kq) ^ (lr & 7)) << 3;
#pragma unroll
  for (int m = 0; m < 4; ++m) aoff[m] = (wm + m * 16 + lr) * 64;
#pragma unroll
  for (int n = 0; n < 2; ++n) boff[n] = (wn + n * 16 + lr) * 64;

#define F1_LD(o, roff, ks) \
  (*reinterpret_cast<const bf16x8*>(&lds[cur][o][(roff) + kread[ks]]))

  f32x4 aS[4][2] = {}, aT[4][2] = {};

  // prologue: stage K-tile 0
  {
    F1_ST(0, 0, 0); F1_ST(0, 1, 0); F1_ST(0, 2, 0); F1_ST(0, 3, 0);
    VMCNT0();
  }
  __syncthreads();

  const int NIT = NB / 64;
  for (int it = 0; it < NIT; ++it) {
    const int cur = it & 1;
    const int nxt = cur ^ 1;
    const bool pf = (it + 1) < NIT;
    const int ktn = (it + 1) * 64;
#pragma unroll
    for (int ks = 0; ks < 2; ++ks) {
      bf16x8 bG[2], bB[2], bBn[2];
#pragma unroll
      for (int mh = 0; mh < 2; ++mh) {
        if (mh == 0) {
          bG[0] = F1_LD(2, boff[0], ks);
          bG[1] = F1_LD(2, boff[1], ks);
          bB[0] = F1_LD(3, boff[0], ks);
          bB[1] = F1_LD(3, boff[1], ks);
          bBn[0] = neg8(bB[0]);
          bBn[1] = neg8(bB[1]);
        }
        bf16x8 au2[2], aw2[2];
#pragma unroll
        for (int i = 0; i < 2; ++i) {
          au2[i] = F1_LD(0, aoff[2 * mh + i], ks);
          aw2[i] = F1_LD(1, aoff[2 * mh + i], ks);
        }
        // prefetch issue in phases 0 and 1 (ks==0)
        if (ks == 0 && pf) {
          if (mh == 0) { F1_ST(nxt, 0, ktn); F1_ST(nxt, 1, ktn); }
          else         { F1_ST(nxt, 2, ktn); F1_ST(nxt, 3, ktn); }
        }
        SBAR();
        SCHEDB();
        __builtin_amdgcn_s_setprio(1);
#pragma unroll
        for (int i = 0; i < 2; ++i) {
          const int m = 2 * mh + i;
#pragma unroll
          for (int n = 0; n < 2; ++n) {
            aS[m][n] = MFMA16(au2[i], bG[n], aS[m][n]);
            aS[m][n] = MFMA16(aw2[i], bBn[n], aS[m][n]);
            aT[m][n] = MFMA16(aw2[i], bG[n], aT[m][n]);
            aT[m][n] = MFMA16(au2[i], bB[n], aT[m][n]);
          }
        }
        __builtin_amdgcn_s_setprio(0);
        SCHEDB();
        if (ks == 1 && mh == 1) VMCNT0();
        SBAR();
        SCHEDB();
      }
    }
  }

  // epilogue: combine with u,w f32 + biases, write p_mid/q_mid bf16
  const int fr = lane & 15, fq = kq;
#pragma unroll
  for (int m = 0; m < 4; ++m)
#pragma unroll
    for (int n = 0; n < 2; ++n)
#pragma unroll
      for (int j = 0; j < 4; ++j) {
        int r = row0 + wm + m * 16 + fq * 4 + j;
        int c = col0 + wn + n * 16 + fr;
        size_t idx = (size_t)r * NB + c;
        float U = u[idx], W = w[idx];
        float S = aS[m][n][j], T = aT[m][n][j];
        pq[idx] = (bf16_t)(U * S + W * T + bias_p[c]);
        pq[SZ + idx] = (bf16_t)(W * S - U * T + bias_q[c]);
      }
}

// ---------------- stage 2: flat ring-4, 2 blocks/CU (r10's v9) -------------
// out_z = pq_z @ W_z^T + b_z (f32). Tile 128x128, 4 waves (2x2, wave 64x64),
// ring-4 (64 KB -> 2 blocks/CU). Per half/wave: 8 ds_read + 4 gload_lds +
// 16 MFMA, one {vmcnt(4); barrier}. Grid 512, XCD-swizzled.
// LDS half layout: [rows][32 k], cell (r,c) at slot c ^ ((r>>1)&3).
__global__ __launch_bounds__(256, 2) void gemm2_v9(
    const bf16_t* __restrict__ pq, const bf16_t* __restrict__ Wpb,
    const bf16_t* __restrict__ Wqb, const float* __restrict__ bp,
    const float* __restrict__ bq, float* __restrict__ out) {
  __shared__ bf16_t lds[4][2][128 * 32];  // [slot][A/W] = 64 KB
  const int tid = threadIdx.x, lane = tid & 63, wv = tid >> 6;
  const int bid = blockIdx.x;
  const int t = (bid & 7) * 64 + (bid >> 3);  // XCD swizzle, 512 blocks
  const int z = t >> 8;
  const int s = t & 255;
  const int row0 = (s & 7) * 128, col0 = (s >> 3) * 128;

  const bf16_t* A = pq + (size_t)z * SZ;
  const bf16_t* Wm = z ? Wqb : Wpb;
  const float* bias = z ? bq : bp;
  float* C = out + (size_t)z * SZ;

  const int wm = (wv >> 1) * 64, wn = (wv & 1) * 64;
  const int lr = lane & 15, kq = lane >> 4;
  const int kswz = (kq ^ ((lr >> 1) & 3)) << 3;

  const int srow = tid >> 2;  // 0..63
  const int sc = (tid & 3) ^ ((tid >> 3) & 3);
  const bf16_t* gA0 = A + (size_t)(row0 + srow) * NB + sc * 8;
  const bf16_t* gA1 = gA0 + (size_t)64 * NB;
  const bf16_t* gW0 = Wm + (size_t)(col0 + srow) * NB + sc * 8;
  const bf16_t* gW1 = gW0 + (size_t)64 * NB;

#define G2_ISSUE(hh)                                                           \
  do {                                                                         \
    const int _sl = (hh) & 3;                                                  \
    const int _ko = (hh) * 32;                                                 \
    GLOAD16(gA0 + _ko, &lds[_sl][0][wv * 512]);                                \
    GLOAD16(gA1 + _ko, &lds[_sl][0][2048 + wv * 512]);                         \
    GLOAD16(gW0 + _ko, &lds[_sl][1][wv * 512]);                                \
    GLOAD16(gW1 + _ko, &lds[_sl][1][2048 + wv * 512]);                         \
  } while (0)

  int aoff[4], woff[4];
#pragma unroll
  for (int m = 0; m < 4; ++m) aoff[m] = (wm + m * 16 + lr) * 32 + kswz;
#pragma unroll
  for (int n = 0; n < 4; ++n) woff[n] = (wn + n * 16 + lr) * 32 + kswz;

  f32x4 acc[4][4] = {};

  G2_ISSUE(0); G2_ISSUE(1); G2_ISSUE(2);
  VMCNT4();
  SBAR();
  SCHEDB();

  const int HTOT = 2 * (NB / 64);
  for (int h = 0; h < HTOT; ++h) {
    const int slot = h & 3;
    const bool pf = (h + 3) < HTOT;

    bf16x8 av[4], bw[4];
#pragma unroll
    for (int m = 0; m < 4; ++m)
      av[m] = *reinterpret_cast<const bf16x8*>(&lds[slot][0][aoff[m]]);
#pragma unroll
    for (int n = 0; n < 4; ++n)
      bw[n] = *reinterpret_cast<const bf16x8*>(&lds[slot][1][woff[n]]);
    if (pf) G2_ISSUE(h + 3);
#pragma unroll
    for (int m = 0; m < 4; ++m)
#pragma unroll
      for (int n = 0; n < 4; ++n)
        acc[m][n] = MFMA16(av[m], bw[n], acc[m][n]);
    if (h < HTOT - 3)
      VMCNT4();
    else if (h == HTOT - 3)
      asm volatile("s_waitcnt vmcnt(2)" ::: "memory");
    else if (h == HTOT - 2)
      VMCNT0();
    SBAR();
    SCHEDB();
  }

  const int fr = lane & 15, fq = kq;
#pragma unroll
  for (int m = 0; m < 4; ++m)
#pragma unroll
    for (int n = 0; n < 4; ++n)
#pragma unroll
      for (int j = 0; j < 4; ++j) {
        int r = row0 + wm + m * 16 + fq * 4 + j;
        int c = col0 + wn + n * 16 + fr;
        C[(size_t)r * NB + c] = acc[m][n][j] + bias[c];
      }
}

// ---------------- fallbacks (compile-only safety net) ----------------
__device__ __forceinline__ int swz_off32(int r, int kk) {
  return r * 32 + ((kk ^ ((r >> 1) & 3)) << 3);
}

__device__ __forceinline__ void fb_stage_f32(const float* __restrict__ src,
                                             int row0, int k0, bf16_t* lds, int t) {
  int r = t >> 2, kk = t & 3;
  const float* p = src + (size_t)(row0 + r) * NB + k0 + (kk << 3);
  float4 v0 = *reinterpret_cast<const float4*>(p);
  float4 v1 = *reinterpret_cast<const float4*>(p + 4);
  *reinterpret_cast<bf16x8*>(lds + swz_off32(r, kk)) = cvt8(v0, v1);
}

__global__ __launch_bounds__(256, 2) void fb_gemm2(
    const bf16_t* __restrict__ pq, const float* __restrict__ Wp,
    const float* __restrict__ Wq, const float* __restrict__ bp,
    const float* __restrict__ bq, float* __restrict__ out) {
  __shared__ bf16_t lA[128 * 32], lW[128 * 32];
  const int z = blockIdx.z;
  const bf16_t* A = pq + (size_t)z * SZ;
  const float* Wm = z ? Wq : Wp;
  const float* bias = z ? bq : bp;
  float* C = out + (size_t)z * SZ;
  const int tid = threadIdx.x;
  const int lane = tid & 63, wv = tid >> 6;
  const int wm = (wv >> 1) * 64, wn = (wv & 1) * 64;
  const int row0 = blockIdx.y * 128, col0 = blockIdx.x * 128;
  const int lr = lane & 15, kq = lane >> 4;
  const int fslot = (kq ^ ((lr >> 1) & 3)) << 3;
  f32x4 acc[4][4] = {};
  for (int kt = 0; kt < NB; kt += 32) {
#pragma unroll
    for (int p = 0; p < 2; ++p) {
      int cb = p * 256 + wv * 64;
      int ci = cb + lane;
      int r = ci >> 2, kl = ci & 3;
      int ks = kl ^ ((r >> 1) & 3);
      const bf16_t* g = A + (size_t)(row0 + r) * NB + kt + (ks << 3);
      GLOAD16(g, lA + cb * 8);
    }
#pragma unroll
    for (int p = 0; p < 2; ++p)
      fb_stage_f32(Wm, col0, kt, lW, p * 256 + tid);
    __syncthreads();
    bf16x8 af[4], bg[4];
#pragma unroll
    for (int m = 0; m < 4; ++m)
      af[m] = *reinterpret_cast<const bf16x8*>(lA + (wm + m * 16 + lr) * 32 + fslot);
#pragma unroll
    for (int n = 0; n < 4; ++n)
      bg[n] = *reinterpret_cast<const bf16x8*>(lW + (wn + n * 16 + lr) * 32 + fslot);
#pragma unroll
    for (int m = 0; m < 4; ++m)
#pragma unroll
      for (int n = 0; n < 4; ++n)
        acc[m][n] = MFMA16(af[m], bg[n], acc[m][n]);
    __syncthreads();
  }
  const int fr = lane & 15, fq = lane >> 4;
#pragma unroll
  for (int m = 0; m < 4; ++m)
#pragma unroll
    for (int n = 0; n < 4; ++n)
#pragma unroll
      for (int j = 0; j < 4; ++j) {
        int r = row0 + wm + m * 16 + fq * 4 + j;
        int c = col0 + wn + n * 16 + fr;
        C[(size_t)r * NB + c] = acc[m][n][j] + bias[c];
      }
}

__global__ __launch_bounds__(512, 2) void fb_fused1(
    const float* __restrict__ u, const float* __restrict__ w,
    const float* __restrict__ G, const float* __restrict__ Bm,
    const float* __restrict__ bias_p, const float* __restrict__ bias_q,
    bf16_t* __restrict__ pq) {
  __shared__ bf16_t lU[128 * 32], lW[128 * 32], lG[128 * 32], lB[128 * 32];
  const int tid = threadIdx.x;
  const int lane = tid & 63, wv = tid >> 6;
  const int wm = (wv >> 2) * 64, wn = (wv & 3) * 32;
  const int row0 = blockIdx.y * 128, col0 = blockIdx.x * 128;
  const int lr = lane & 15, kq = lane >> 4;
  const int fslot = (kq ^ ((lr >> 1) & 3)) << 3;
  f32x4 aS[4][2] = {}, aT[4][2] = {};
  for (int kt = 0; kt < NB; kt += 32) {
    fb_stage_f32(u, row0, kt, lU, tid);
    fb_stage_f32(w, row0, kt, lW, tid);
    fb_stage_f32(G, col0, kt, lG, tid);
    fb_stage_f32(Bm, col0, kt, lB, tid);
    __syncthreads();
    bf16x8 au[4], aw[4], bG[2], bB[2], bBn[2];
#pragma unroll
    for (int m = 0; m < 4; ++m) {
      int off = (wm + m * 16 + lr) * 32 + fslot;
      au[m] = *reinterpret_cast<const bf16x8*>(lU + off);
      aw[m] = *reinterpret_cast<const bf16x8*>(lW + off);
    }
#pragma unroll
    for (int n = 0; n < 2; ++n) {
      int off = (wn + n * 16 + lr) * 32 + fslot;
      bG[n] = *reinterpret_cast<const bf16x8*>(lG + off);
      bB[n] = *reinterpret_cast<const bf16x8*>(lB + off);
      bBn[n] = neg8(bB[n]);
    }
#pragma unroll
    for (int m = 0; m < 4; ++m)
#pragma unroll
      for (int n = 0; n < 2; ++n) {
        aS[m][n] = MFMA16(au[m], bG[n], aS[m][n]);
        aS[m][n] = MFMA16(aw[m], bBn[n], aS[m][n]);
        aT[m][n] = MFMA16(aw[m], bG[n], aT[m][n]);
        aT[m][n] = MFMA16(au[m], bB[n], aT[m][n]);
      }
    __syncthreads();
  }
  const int fr = lane & 15, fq = lane >> 4;
#pragma unroll
  for (int m = 0; m < 4; ++m)
#pragma unroll
    for (int n = 0; n < 2; ++n)
#pragma unroll
      for (int j = 0; j < 4; ++j) {
        int r = row0 + wm + m * 16 + fq * 4 + j;
        int c = col0 + wn + n * 16 + fr;
        size_t idx = (size_t)r * NB + c;
        float U = u[idx], W = w[idx];
        float S = aS[m][n][j], T = aT[m][n][j];
        pq[idx] = (bf16_t)(U * S + W * T + bias_p[c]);
        pq[SZ + idx] = (bf16_t)(W * S - U * T + bias_q[c]);
      }
}

extern "C" void kernel_launch(void* const* d_in, const int* in_sizes, int n_in,
                              void* d_out, int out_size, void* d_ws, size_t ws_size,
                              hipStream_t stream) {
  const float* u = (const float*)d_in[0];
  const float* w = (const float*)d_in[1];
  const float* G = (const float*)d_in[2];
  const float* Bm = (const float*)d_in[3];
  const float* bias_p = (const float*)d_in[4];
  const float* bias_q = (const float*)d_in[5];
  const float* Wp = (const float*)d_in[6];
  const float* bp = (const float*)d_in[7];
  const float* Wq = (const float*)d_in[8];
  const float* bq = (const float*)d_in[9];
  (void)in_sizes; (void)n_in; (void)out_size;

  const size_t need_full = (6 * SZ + 4 * NN) * sizeof(bf16_t);  // 176 MB
  const size_t need_mid = (6 * SZ + 2 * NN) * sizeof(bf16_t);   // 112 MB

  if (ws_size >= need_full) {
    bf16_t* ws = (bf16_t*)d_ws;
    bf16_t* ubf = ws;
    bf16_t* wbf = ws + SZ;
    bf16_t* Gbf = ws + 2 * SZ;
    bf16_t* Bbf = Gbf + NN;
    bf16_t* Wpb = Bbf + NN;
    bf16_t* Wqb = Wpb + NN;
    bf16_t* pqw = Wqb + NN;
    prep6_kernel<<<2048, 256, 0, stream>>>(u, w, G, Bm, Wp, Wq, ws);
    fused1_v3<<<256, 512, 0, stream>>>(u, w, ubf, wbf, Gbf, Bbf,
                                       bias_p, bias_q, pqw);
    gemm2_v9<<<512, 256, 0, stream>>>(pqw, Wpb, Wqb, bp, bq, (float*)d_out);
  } else if (ws_size >= need_mid) {
    bf16_t* ws = (bf16_t*)d_ws;
    bf16_t* ubf = ws;
    bf16_t* wbf = ws + SZ;
    bf16_t* Gbf = ws + 2 * SZ;
    bf16_t* Bbf = Gbf + NN;
    bf16_t* pqw = Bbf + NN;
    prep4_kernel<<<2048, 256, 0, stream>>>(u, w, G, Bm, ws);
    fused1_v3<<<256, 512, 0, stream>>>(u, w, ubf, wbf, Gbf, Bbf,
                                       bias_p, bias_q, pqw);
    fb_gemm2<<<dim3(NB / 128, MB / 128, 2), 256, 0, stream>>>(
        pqw, Wp, Wq, bp, bq, (float*)d_out);
  } else {
    bf16_t* pqw = (bf16_t*)d_ws;
    fb_fused1<<<dim3(NB / 128, MB / 128), 512, 0, stream>>>(
        u, w, G, Bm, bias_p, bias_q, pqw);
    fb_gemm2<<<dim3(NB / 128, MB / 128, 2), 256, 0, stream>>>(
        pqw, Wp, Wq, bp, bq, (float*)d_out);
  }
}